// Round 3
// baseline (210.666 us; speedup 1.0000x reference)
//
#include <hip/hip_runtime.h>

typedef short bf16x8 __attribute__((ext_vector_type(8)));
typedef float f32x4 __attribute__((ext_vector_type(4)));
typedef unsigned short u16;

#define NNODE 196608
#define FF 32
#define KK 9
#define COLS 256   // UP * OUT_FEATURES
#define KTOT 288   // KK * FF
#define WELEMS (COLS * KTOT)   // 73728 elems = 144 KB bf16

__device__ __forceinline__ u16 f2bf(float f) {
    unsigned u = __builtin_bit_cast(unsigned, f);
    return (u16)((u + 0x7fffu + ((u >> 16) & 1u)) >> 16);  // RTNE
}

// prep 1: x f32 -> bf16, 8 elems/thread
__global__ void cvt_x(const float* __restrict__ x, u16* __restrict__ xb, int n8) {
    int i = blockIdx.x * blockDim.x + threadIdx.x;
    if (i >= n8) return;
    f32x4 v0 = *((const f32x4*)x + (size_t)i * 2);
    f32x4 v1 = *((const f32x4*)x + (size_t)i * 2 + 1);
    union { u16 h[8]; bf16x8 v; } r;
    #pragma unroll
    for (int j = 0; j < 4; ++j) r.h[j] = f2bf(v0[j]);
    #pragma unroll
    for (int j = 0; j < 4; ++j) r.h[4 + j] = f2bf(v1[j]);
    *((bf16x8*)xb + i) = r.v;
}

// prep 2: W (K,F,UP,O) f32 -> Wt bf16 in MFMA B-FRAGMENT-LINEAR order.
// Frag tile f = kk*16 + ct (ct = col-tile) occupies 512 elems (1024 B):
//   position = f*512 + lane*8 + e, where lane = (c&15) + ((kf>>3)&3)*16,
//   e = kf&7, c = ct*16 + (c&15), kf = kk*32 + ((kf>>3)&3)*8 + e.
// A wave's ds_read_b128 of one fragment is then lane-linear: ZERO conflicts.
__global__ void cvt_w(const float* __restrict__ W, u16* __restrict__ Wt) {
    int gid = blockIdx.x * 256 + threadIdx.x;   // 73728 total
    int f      = gid >> 9;          // 0..143
    int within = gid & 511;
    int lane   = within >> 3;
    int e      = within & 7;
    int kk = f >> 4, ct = f & 15;
    int cl = lane & 15, q = lane >> 4;
    int c  = ct * 16 + cl;
    int kf = kk * 32 + q * 8 + e;
    Wt[gid] = f2bf(W[(size_t)kf * COLS + c]);
}

// main: 512 threads = 8 waves. Block tile 256 rows x 256 cols.
// Wave (wr = w>>2, wc = w&3): 128 rows x 64 cols (mt=8, nt=4).
// W fully LDS-resident in fragment-linear order; ONE barrier; K-loop has
// no barriers, no ds_writes, conflict-free lane-linear ds_read_b128.
__global__ __launch_bounds__(512, 2) void updown_main(
    const u16* __restrict__ xb, const u16* __restrict__ Wt,
    const int* __restrict__ adjc, const float* __restrict__ bias,
    float* __restrict__ out)
{
    __shared__ __align__(16) u16 wlds[WELEMS];   // 144 KB, read-only after load

    const int tid = threadIdx.x;

    // cooperative W copy: 18 x 8 KB, coalesced, layout-agnostic (linear)
    #pragma unroll
    for (int i = 0; i < 18; ++i) {
        *(bf16x8*)(wlds + i * 4096 + tid * 8) =
            *(const bf16x8*)(Wt + i * 4096 + tid * 8);
    }

    const int w    = tid >> 6;
    const int lane = tid & 63;
    const int l15  = lane & 15;
    const int q    = lane >> 4;
    const int wr   = w >> 2;            // 0..1
    const int wc   = w & 3;             // 0..3
    const int blk  = blockIdx.x;
    const int t    = (blk >= 768) ? 1 : 0;
    const int nb   = (blk - t * 768) * 256 + wr * 128;  // node base for wave
    const int cb   = wc * 64;                           // col base
    const u16* xbt = xb + (size_t)t * NNODE * FF;

    // idx pipeline (1 deep beyond current) + A-gather pipeline (1 deep)
    int idxN[8];
    bf16x8 aC[8];
    #pragma unroll
    for (int mt = 0; mt < 8; ++mt) {
        int i0 = adjc[(size_t)(nb + mt * 16 + l15) * 9 + 0];
        aC[mt] = *(const bf16x8*)(xbt + (size_t)i0 * FF + q * 8);
    }
    #pragma unroll
    for (int mt = 0; mt < 8; ++mt)
        idxN[mt] = adjc[(size_t)(nb + mt * 16 + l15) * 9 + 1];

    f32x4 acc[8][4];
    #pragma unroll
    for (int mt = 0; mt < 8; ++mt)
        #pragma unroll
        for (int nt = 0; nt < 4; ++nt)
            acc[mt][nt] = (f32x4){0.f, 0.f, 0.f, 0.f};

    __syncthreads();   // W resident; no further barriers

    // per-lane LDS base: wave's col-group frag tiles, lane-linear
    const u16* bb0 = wlds + (size_t)(wc * 4) * 512 + lane * 8;

    #pragma unroll
    for (int kk = 0; kk < 9; ++kk) {
        bf16x8 aNv[8];
        if (kk < 8) {
            // gather A for step kk+1; refill idx for kk+2
            #pragma unroll
            for (int mt = 0; mt < 8; ++mt)
                aNv[mt] = *(const bf16x8*)(xbt + (size_t)idxN[mt] * FF + q * 8);
            if (kk < 7) {
                #pragma unroll
                for (int mt = 0; mt < 8; ++mt)
                    idxN[mt] = adjc[(size_t)(nb + mt * 16 + l15) * 9 + (kk + 2)];
            }
        }

        const u16* bk = bb0 + kk * 8192;   // kk*16 frag tiles * 512 elems
        bf16x8 bf[4];
        #pragma unroll
        for (int nt = 0; nt < 4; ++nt)
            bf[nt] = *(const bf16x8*)(bk + nt * 512);

        #pragma unroll
        for (int mt = 0; mt < 8; ++mt)
            #pragma unroll
            for (int nt = 0; nt < 4; ++nt)
                acc[mt][nt] = __builtin_amdgcn_mfma_f32_16x16x32_bf16(
                    aC[mt], bf[nt], acc[mt][nt], 0, 0, 0);

        if (kk < 8) {
            #pragma unroll
            for (int mt = 0; mt < 8; ++mt) aC[mt] = aNv[mt];
        }
    }

    // epilogue: bias + store (C/D: col = lane&15, row = q*4 + reg)
    float bb[4];
    #pragma unroll
    for (int nt = 0; nt < 4; ++nt) bb[nt] = bias[cb + nt * 16 + l15];

    const size_t rowbase = (size_t)t * NNODE + nb;
    #pragma unroll
    for (int mt = 0; mt < 8; ++mt) {
        #pragma unroll
        for (int nt = 0; nt < 4; ++nt) {
            #pragma unroll
            for (int r = 0; r < 4; ++r) {
                out[(rowbase + mt * 16 + q * 4 + r) * COLS + cb + nt * 16 + l15]
                    = acc[mt][nt][r] + bb[nt];
            }
        }
    }
}

extern "C" void kernel_launch(void* const* d_in, const int* in_sizes, int n_in,
                              void* d_out, int out_size, void* d_ws, size_t ws_size,
                              hipStream_t stream) {
    const float* x    = (const float*)d_in[0];
    const int*   adjc = (const int*)d_in[1];
    const float* W    = (const float*)d_in[2];
    const float* b    = (const float*)d_in[3];
    float* out = (float*)d_out;

    u16* xb = (u16*)d_ws;                            // 2*196608*32 bf16 = 25.2 MB
    u16* Wt = xb + (size_t)2 * NNODE * FF;           // 73728 bf16 = 144 KB

    cvt_x<<<dim3(6144), dim3(256), 0, stream>>>(x, xb, 1572864);
    cvt_w<<<dim3(288), dim3(256), 0, stream>>>(W, Wt);
    updown_main<<<dim3(1536), dim3(512), 0, stream>>>(xb, Wt, adjc, b, out);
}

// Round 4
// 176.016 us; speedup vs baseline: 1.1969x; 1.1969x over previous
//
#include <hip/hip_runtime.h>

typedef short bf16x8 __attribute__((ext_vector_type(8)));
typedef float f32x4 __attribute__((ext_vector_type(4)));
typedef unsigned short u16;

#define NNODE 196608
#define FF 32
#define KK 9
#define COLS 256   // UP * OUT_FEATURES
#define KTOT 288   // KK * FF
#define WELEMS (COLS * KTOT)   // 73728 elems = 144 KB bf16

__device__ __forceinline__ u16 f2bf(float f) {
    unsigned u = __builtin_bit_cast(unsigned, f);
    return (u16)((u + 0x7fffu + ((u >> 16) & 1u)) >> 16);  // RTNE
}

// prep 1: x f32 -> bf16, 8 elems/thread
__global__ void cvt_x(const float* __restrict__ x, u16* __restrict__ xb, int n8) {
    int i = blockIdx.x * blockDim.x + threadIdx.x;
    if (i >= n8) return;
    f32x4 v0 = *((const f32x4*)x + (size_t)i * 2);
    f32x4 v1 = *((const f32x4*)x + (size_t)i * 2 + 1);
    union { u16 h[8]; bf16x8 v; } r;
    #pragma unroll
    for (int j = 0; j < 4; ++j) r.h[j] = f2bf(v0[j]);
    #pragma unroll
    for (int j = 0; j < 4; ++j) r.h[4 + j] = f2bf(v1[j]);
    *((bf16x8*)xb + i) = r.v;
}

// prep 2: W (K,F,UP,O) f32 -> Wt bf16 in MFMA B-FRAGMENT-LINEAR order.
// Frag f = kk*16 + ct occupies 512 elems (1024 B), lane-linear:
//   Wt[f*512 + lane*8 + e] = W[kf][c], c = ct*16 + (lane&15),
//   kf = kk*32 + (lane>>4)*8 + e.  ds_read_b128 of a frag: ZERO conflicts.
__global__ void cvt_w(const float* __restrict__ W, u16* __restrict__ Wt) {
    int gid = blockIdx.x * 256 + threadIdx.x;   // 73728 total
    int f      = gid >> 9;          // 0..143
    int within = gid & 511;
    int lane   = within >> 3;
    int e      = within & 7;
    int kk = f >> 4, ct = f & 15;
    int cl = lane & 15, q = lane >> 4;
    int c  = ct * 16 + cl;
    int kf = kk * 32 + q * 8 + e;
    Wt[gid] = f2bf(W[(size_t)kf * COLS + c]);
}

// main: 512 threads = 8 waves, block tile 256 rows x 256 cols.
// Wave (wr = w>>1, wc = w&1): 64 rows x 128 cols (mt=4, nt=8) — gather
// redundancy 2x (best measured), conflict-free frag-linear LDS reads.
// W fully LDS-resident; ONE barrier; barrier-free K-loop.
__global__ __launch_bounds__(512, 2) void updown_main(
    const u16* __restrict__ xb, const u16* __restrict__ Wt,
    const int* __restrict__ adjc, const float* __restrict__ bias,
    float* __restrict__ out)
{
    __shared__ __align__(16) u16 wlds[WELEMS];   // 144 KB, read-only after load

    const int tid = threadIdx.x;

    // cooperative W copy: 18 x 8 KB, coalesced, linear both sides
    #pragma unroll
    for (int i = 0; i < 18; ++i) {
        *(bf16x8*)(wlds + i * 4096 + tid * 8) =
            *(const bf16x8*)(Wt + i * 4096 + tid * 8);
    }

    const int w    = tid >> 6;
    const int lane = tid & 63;
    const int l15  = lane & 15;
    const int q    = lane >> 4;
    const int wr   = w >> 1;            // 0..3
    const int wc   = w & 1;             // 0..1
    const int blk  = blockIdx.x;
    const int t    = (blk >= 768) ? 1 : 0;
    const int nb   = (blk - t * 768) * 256 + wr * 64;   // node base for wave
    const int cb   = wc * 128;                          // col base
    const u16* xbt = xb + (size_t)t * NNODE * FF;

    // pipeline: A-gather 1 deep, idx 1 deep beyond that
    int idxN[4];
    bf16x8 aC[4];
    #pragma unroll
    for (int mt = 0; mt < 4; ++mt) {
        int i0 = adjc[(size_t)(nb + mt * 16 + l15) * 9 + 0];
        aC[mt] = *(const bf16x8*)(xbt + (size_t)i0 * FF + q * 8);
    }
    #pragma unroll
    for (int mt = 0; mt < 4; ++mt)
        idxN[mt] = adjc[(size_t)(nb + mt * 16 + l15) * 9 + 1];

    f32x4 acc[4][8];
    #pragma unroll
    for (int mt = 0; mt < 4; ++mt)
        #pragma unroll
        for (int nt = 0; nt < 8; ++nt)
            acc[mt][nt] = (f32x4){0.f, 0.f, 0.f, 0.f};

    __syncthreads();   // W resident; no further barriers

    // per-lane LDS base: this wave's 8 col-tiles start at frag wc*8
    const u16* bb0 = wlds + (size_t)(wc * 8) * 512 + lane * 8;

    #pragma unroll
    for (int kk = 0; kk < 9; ++kk) {
        bf16x8 aNv[4];
        if (kk < 8) {
            #pragma unroll
            for (int mt = 0; mt < 4; ++mt)
                aNv[mt] = *(const bf16x8*)(xbt + (size_t)idxN[mt] * FF + q * 8);
            if (kk < 7) {
                #pragma unroll
                for (int mt = 0; mt < 4; ++mt)
                    idxN[mt] = adjc[(size_t)(nb + mt * 16 + l15) * 9 + (kk + 2)];
            }
        }

        const u16* bk = bb0 + kk * 8192;   // 16 frags per k-step * 512 elems
        bf16x8 bf[8];
        #pragma unroll
        for (int nt = 0; nt < 8; ++nt)
            bf[nt] = *(const bf16x8*)(bk + nt * 512);

        #pragma unroll
        for (int mt = 0; mt < 4; ++mt)
            #pragma unroll
            for (int nt = 0; nt < 8; ++nt)
                acc[mt][nt] = __builtin_amdgcn_mfma_f32_16x16x32_bf16(
                    aC[mt], bf[nt], acc[mt][nt], 0, 0, 0);

        if (kk < 8) {
            #pragma unroll
            for (int mt = 0; mt < 4; ++mt) aC[mt] = aNv[mt];
        }
    }

    // epilogue: bias + nontemporal store (don't evict xb from L2/L3)
    float bb[8];
    #pragma unroll
    for (int nt = 0; nt < 8; ++nt) bb[nt] = bias[cb + nt * 16 + l15];

    const size_t rowbase = (size_t)t * NNODE + nb;
    #pragma unroll
    for (int mt = 0; mt < 4; ++mt) {
        #pragma unroll
        for (int nt = 0; nt < 8; ++nt) {
            #pragma unroll
            for (int r = 0; r < 4; ++r) {
                __builtin_nontemporal_store(
                    acc[mt][nt][r] + bb[nt],
                    &out[(rowbase + mt * 16 + q * 4 + r) * COLS + cb + nt * 16 + l15]);
            }
        }
    }
}

extern "C" void kernel_launch(void* const* d_in, const int* in_sizes, int n_in,
                              void* d_out, int out_size, void* d_ws, size_t ws_size,
                              hipStream_t stream) {
    const float* x    = (const float*)d_in[0];
    const int*   adjc = (const int*)d_in[1];
    const float* W    = (const float*)d_in[2];
    const float* b    = (const float*)d_in[3];
    float* out = (float*)d_out;

    u16* xb = (u16*)d_ws;                            // 2*196608*32 bf16 = 25.2 MB
    u16* Wt = xb + (size_t)2 * NNODE * FF;           // 73728 bf16 = 144 KB

    cvt_x<<<dim3(6144), dim3(256), 0, stream>>>(x, xb, 1572864);
    cvt_w<<<dim3(288), dim3(256), 0, stream>>>(W, Wt);
    updown_main<<<dim3(1536), dim3(512), 0, stream>>>(xb, Wt, adjc, b, out);
}

// Round 5
// 157.033 us; speedup vs baseline: 1.3415x; 1.1209x over previous
//
#include <hip/hip_runtime.h>

typedef short bf16x8 __attribute__((ext_vector_type(8)));
typedef float f32x4 __attribute__((ext_vector_type(4)));
typedef unsigned short u16;

#define NNODE 196608
#define FF 32
#define COLS 256   // UP * OUT_FEATURES
#define KTOT 288   // KK * FF
#define WELEMS (COLS * KTOT)   // 73728 elems = 144 KB bf16
#define NTILES 1536            // 196608 nodes / 128 nodes per tile

__device__ __forceinline__ u16 f2bf(float f) {
    unsigned u = __builtin_bit_cast(unsigned, f);
    return (u16)((u + 0x7fffu + ((u >> 16) & 1u)) >> 16);  // RTNE
}

__global__ void reset_ctr(unsigned* c) { *c = 0u; }

// prep 1: x f32 -> bf16, 8 elems/thread
__global__ void cvt_x(const float* __restrict__ x, u16* __restrict__ xb, int n8) {
    int i = blockIdx.x * blockDim.x + threadIdx.x;
    if (i >= n8) return;
    f32x4 v0 = *((const f32x4*)x + (size_t)i * 2);
    f32x4 v1 = *((const f32x4*)x + (size_t)i * 2 + 1);
    union { u16 h[8]; bf16x8 v; } r;
    #pragma unroll
    for (int j = 0; j < 4; ++j) r.h[j] = f2bf(v0[j]);
    #pragma unroll
    for (int j = 0; j < 4; ++j) r.h[4 + j] = f2bf(v1[j]);
    *((bf16x8*)xb + i) = r.v;
}

// prep 2: W (K,F,UP,O) f32 -> Wt bf16 in MFMA B-FRAGMENT-LINEAR order.
// Frag f = kk*16 + ct occupies 512 elems (1024 B), lane-linear:
//   Wt[f*512 + lane*8 + e] = W[kf][c], c = ct*16 + (lane&15),
//   kf = kk*32 + (lane>>4)*8 + e.  ds_read_b128 of a frag: ZERO conflicts.
__global__ void cvt_w(const float* __restrict__ W, u16* __restrict__ Wt) {
    int gid = blockIdx.x * 256 + threadIdx.x;   // 73728 total
    int f      = gid >> 9;          // 0..143
    int within = gid & 511;
    int lane   = within >> 3;
    int e      = within & 7;
    int kk = f >> 4, ct = f & 15;
    int cl = lane & 15, q = lane >> 4;
    int c  = ct * 16 + cl;
    int kf = kk * 32 + q * 8 + e;
    Wt[gid] = f2bf(W[(size_t)kf * COLS + c]);
}

// main: PERSISTENT — grid 256, one block/CU, W in LDS once.
// Tile = 128 nodes x 2 time-slices x 256 cols. 8 waves x 16 nodes each.
// Wave: mt=2 (t0/t1 share adjc idx -> gather redundancy C=1), nt=16.
// Work-stealing via atomic counter; raw s_barrier (NO vmcnt drain) so
// stores of tile i overlap compute of tile i+1.
__global__ __launch_bounds__(512, 2) void updown_main(
    const u16* __restrict__ xb, const u16* __restrict__ Wt,
    const int* __restrict__ adjc, const float* __restrict__ bias,
    float* __restrict__ out, unsigned* __restrict__ ctr)
{
    __shared__ __align__(16) u16 wlds[WELEMS];   // 144 KB, read-only after load
    __shared__ int sTile[2];

    const int tid = threadIdx.x;

    // cooperative W copy: 18 x 8 KB, coalesced, linear both sides — ONCE
    #pragma unroll
    for (int i = 0; i < 18; ++i) {
        *(bf16x8*)(wlds + i * 4096 + tid * 8) =
            *(const bf16x8*)(Wt + i * 4096 + tid * 8);
    }

    const int w    = tid >> 6;
    const int lane = tid & 63;
    const int l15  = lane & 15;
    const int q    = lane >> 4;

    float bb[16];
    #pragma unroll
    for (int nt = 0; nt < 16; ++nt) bb[nt] = bias[nt * 16 + l15];

    const u16* bbase = wlds + lane * 8;            // + kk*8192 + nt*512
    const u16* xb1   = xb + (size_t)NNODE * FF;    // t=1 slice

    if (tid == 0) sTile[0] = (int)atomicAdd(ctr, 1u);
    __syncthreads();   // W resident + first tile id visible (full drain OK once)

    int it = 0;
    for (;;) {
        const int p    = it & 1;
        const int tile = sTile[p];
        if (tile >= NTILES) break;
        // steal NEXT tile now; latency hides under this tile's compute
        if (tid == 0) sTile[p ^ 1] = (int)atomicAdd(ctr, 1u);

        const int  node = tile * 128 + w * 16 + l15;   // per-lane node id
        const int* arow = adjc + (size_t)node * 9;

        int i0   = arow[0];
        int idxN = arow[1];
        bf16x8 aC0 = *(const bf16x8*)(xb  + (size_t)i0 * FF + q * 8);
        bf16x8 aC1 = *(const bf16x8*)(xb1 + (size_t)i0 * FF + q * 8);

        f32x4 acc0[16], acc1[16];
        #pragma unroll
        for (int nt = 0; nt < 16; ++nt) {
            acc0[nt] = (f32x4){0.f, 0.f, 0.f, 0.f};
            acc1[nt] = (f32x4){0.f, 0.f, 0.f, 0.f};
        }

        #pragma unroll
        for (int kk = 0; kk < 9; ++kk) {
            bf16x8 aN0, aN1;
            if (kk < 8) {
                aN0 = *(const bf16x8*)(xb  + (size_t)idxN * FF + q * 8);
                aN1 = *(const bf16x8*)(xb1 + (size_t)idxN * FF + q * 8);
                if (kk < 7) idxN = arow[kk + 2];
            }
            const u16* bk = bbase + kk * 8192;   // frag-linear: kk*16 frags
            #pragma unroll
            for (int nt = 0; nt < 16; ++nt) {
                bf16x8 bf = *(const bf16x8*)(bk + nt * 512);
                acc0[nt] = __builtin_amdgcn_mfma_f32_16x16x32_bf16(aC0, bf, acc0[nt], 0, 0, 0);
                acc1[nt] = __builtin_amdgcn_mfma_f32_16x16x32_bf16(aC1, bf, acc1[nt], 0, 0, 0);
            }
            if (kk < 8) { aC0 = aN0; aC1 = aN1; }
        }

        // epilogue: bias + plain stores (C/D: col = lane&15, row = q*4 + reg)
        const size_t r0 = (size_t)tile * 128 + w * 16 + q * 4;
        #pragma unroll
        for (int nt = 0; nt < 16; ++nt) {
            #pragma unroll
            for (int r = 0; r < 4; ++r) {
                out[(r0 + r) * COLS + nt * 16 + l15]                   = acc0[nt][r] + bb[nt];
                out[(r0 + r + (size_t)NNODE) * COLS + nt * 16 + l15]   = acc1[nt][r] + bb[nt];
            }
        }

        // end-of-tile rendezvous: raw barrier, NO vmcnt drain (stores fly on)
        asm volatile("s_waitcnt lgkmcnt(0)" ::: "memory");
        __builtin_amdgcn_s_barrier();
        asm volatile("" ::: "memory");
        ++it;
    }
}

extern "C" void kernel_launch(void* const* d_in, const int* in_sizes, int n_in,
                              void* d_out, int out_size, void* d_ws, size_t ws_size,
                              hipStream_t stream) {
    const float* x    = (const float*)d_in[0];
    const int*   adjc = (const int*)d_in[1];
    const float* W    = (const float*)d_in[2];
    const float* b    = (const float*)d_in[3];
    float* out = (float*)d_out;

    u16* xb = (u16*)d_ws;                            // 2*196608*32 bf16 = 25.2 MB
    u16* Wt = xb + (size_t)2 * NNODE * FF;           // 73728 bf16 = 144 KB
    unsigned* ctr = (unsigned*)(Wt + WELEMS);        // 4 B work-steal counter

    reset_ctr<<<dim3(1), dim3(1), 0, stream>>>(ctr);
    cvt_x<<<dim3(6144), dim3(256), 0, stream>>>(x, xb, 1572864);
    cvt_w<<<dim3(288), dim3(256), 0, stream>>>(W, Wt);
    updown_main<<<dim3(256), dim3(512), 0, stream>>>(xb, Wt, adjc, b, out, ctr);
}